// Round 15
// baseline (460.296 us; speedup 1.0000x reference)
//
#include <hip/hip_runtime.h>
#include <hip/hip_bf16.h>

// Problem constants
#define Bn 2
#define INCH 256
#define OUTCH 128
#define Hs 96
#define Ws 96
#define HW (Hs*Ws)          // 9216
#define N9 9

typedef __attribute__((ext_vector_type(8))) short bf16x8;
typedef __attribute__((ext_vector_type(4))) float f32x4;

static __device__ inline ushort bfbits(float v) {
    __hip_bfloat16 h = __float2bfloat16(v);
    return *reinterpret_cast<ushort*>(&h);
}
static __device__ inline float bf2f(ushort u) {
    __hip_bfloat16 h = *reinterpret_cast<__hip_bfloat16*>(&u);
    return __bfloat162float(h);
}
static __device__ inline uint packu(ushort lo, ushort hi) {
    return (uint)lo | ((uint)hi << 16);
}
// NHWC packed value: uint = hi_bits | (lo_bits<<16); reconstruct f32 halves:
static __device__ inline float rchi(uint u) { return __uint_as_float(u << 16); }
static __device__ inline float rclo(uint u) { return __uint_as_float(u & 0xffff0000u); }

// ---------------- bilinear 2x upsample, align_corners=True ----------------
__global__ void up2_kernel(const float* __restrict__ in, float* __restrict__ out) {
    int idx = blockIdx.x * blockDim.x + threadIdx.x;
    const int total = Bn * INCH * HW;
    if (idx >= total) return;
    int xo = idx % Ws;
    int yo = (idx / Ws) % Hs;
    int bc = idx / HW;
    const float s = 47.0f / 95.0f;
    float yf = yo * s, xf = xo * s;
    int y0 = (int)floorf(yf); int y1 = min(y0 + 1, 47);
    int x0 = (int)floorf(xf); int x1 = min(x0 + 1, 47);
    float wy = yf - (float)y0, wx = xf - (float)x0;
    const float* p = in + (size_t)bc * 2304;
    float r0 = p[y0*48 + x0] * (1.f - wy) + p[y1*48 + x0] * wy;
    float r1 = p[y0*48 + x1] * (1.f - wy) + p[y1*48 + x1] * wy;
    out[idx] = r0 * (1.f - wx) + r1 * wx;
}

// ---------------- NCHW f32 -> NHWC packed bf16 (hi|lo<<16) transpose ----------------
template<int C>
__global__ void t_nhwc_kernel(const float* __restrict__ in, uint* __restrict__ out) {
    __shared__ float t[32][33];
    constexpr int PB = HW / 32;          // 288
    int blk = blockIdx.x;
    int p0 = (blk % PB) * 32;
    int c0 = ((blk / PB) % (C / 32)) * 32;
    int b = blk / (PB * (C / 32));
    int tp = threadIdx.x & 31, tg = threadIdx.x >> 5;   // tg 0..7
    #pragma unroll
    for (int r = 0; r < 4; r++) {
        int c = c0 + tg + r * 8;
        t[tg + r * 8][tp] = in[((size_t)b * C + c) * HW + p0 + tp];
    }
    __syncthreads();
    #pragma unroll
    for (int r = 0; r < 4; r++) {
        int p = p0 + tg + r * 8;
        float v = t[tp][tg + r * 8];
        ushort h = bfbits(v);
        ushort l = bfbits(v - bf2f(h));
        out[((size_t)b * HW + p) * C + c0 + tp] = packu(h, l);
    }
}

// ---------------- copy x1 into channels [128..256) of concat buffer ----------------
__global__ void copy_x1_kernel(const float* __restrict__ x1, float* __restrict__ xcat) {
    int idx = blockIdx.x * blockDim.x + threadIdx.x;
    const int total = Bn * OUTCH * HW;
    if (idx >= total) return;
    int b = idx / (OUTCH * HW);
    int r = idx % (OUTCH * HW);
    xcat[((size_t)b * INCH + OUTCH) * HW + r] = x1[idx];
}

// ---------------- offset conv (3x3, pad=1, COUT=18) fp32, channel-split partials -------
template<int CIN, int SPLIT>
__global__ void offconv_kernel(const float* __restrict__ in, const float* __restrict__ w,
                               float* __restrict__ part) {
    constexpr int CS = CIN / SPLIT;
    constexpr int BPS = Bn * HW / 256;   // 72
    int s = blockIdx.x / BPS;
    int p = (blockIdx.x % BPS) * 256 + threadIdx.x;
    int b = p / HW; int pin = p % HW;
    int i = pin / Ws, j = pin % Ws;
    const float* ib = in + ((size_t)b * CIN + s * CS) * HW;
    const float* wb = w + (size_t)s * CS * N9;
    float acc[18];
    #pragma unroll
    for (int o = 0; o < 18; o++) acc[o] = 0.f;
    for (int c = 0; c < CS; c++) {
        float v[9];
        #pragma unroll
        for (int n = 0; n < 9; n++) {
            int rr = i + n / 3 - 1, cc = j + n % 3 - 1;
            v[n] = (rr >= 0 && rr < Hs && cc >= 0 && cc < Ws) ? ib[(size_t)c * HW + rr * Ws + cc] : 0.f;
        }
        const float* wc = wb + (size_t)c * N9;
        #pragma unroll
        for (int o = 0; o < 18; o++) {
            #pragma unroll
            for (int n = 0; n < 9; n++) acc[o] += wc[(size_t)o * CIN * N9 + n] * v[n];
        }
    }
    #pragma unroll
    for (int o = 0; o < 18; o++)
        part[(((size_t)s * Bn + b) * 18 + o) * HW + pin] = acc[o];
}

template<int SPLIT>
__global__ void offreduce_kernel(const float* __restrict__ part, const float* __restrict__ bias,
                                 float* __restrict__ off) {
    int idx = blockIdx.x * blockDim.x + threadIdx.x;
    const int total = Bn * 18 * HW;
    if (idx >= total) return;
    int pin = idx % HW;
    int o = (idx / HW) % 18;
    int b = idx / (18 * HW);
    float a = bias[o];
    #pragma unroll
    for (int s = 0; s < SPLIT; s++) a += part[(((size_t)s * Bn + b) * 18 + o) * HW + pin];
    off[((size_t)b * 18 + o) * HW + pin] = a;
}

// ------ weight prep: [oc][c][3][3] fp32 -> bf16 hi[k/32][128][32] ++ lo; k = n*CIN + c ------
template<int CIN>
__global__ void wprep_big_kernel(const float* __restrict__ cw, ushort* __restrict__ wp) {
    int e = blockIdx.x * 256 + threadIdx.x;
    if (e >= CIN * 9 * 128) return;
    int kl = e & 31, oc = (e >> 5) & 127, k32 = e >> 12;
    int k = k32 * 32 + kl;
    int n = k / CIN, c = k & (CIN - 1);
    float v = cw[((size_t)oc * CIN + c) * 9 + n];
    ushort h = bfbits(v);
    wp[e] = h;
    wp[e + CIN * 9 * 128] = bfbits(v - bf2f(h));
}

// ---------------- sampling params: indices + bilinear weights ----------------
__global__ void mkparams_kernel(const float* __restrict__ off, int4* __restrict__ pidx,
                                float4* __restrict__ pw) {
    int e = blockIdx.x * blockDim.x + threadIdx.x;
    const int total = Bn * HW * N9;
    if (e >= total) return;
    int n = e % N9;
    int p = e / N9;
    int j = p % Ws;
    int i = (p / Ws) % Hs;
    int b = p / HW;
    float ox = off[((size_t)b * 18 + n) * HW + i * Ws + j];
    float oy = off[((size_t)b * 18 + 9 + n) * HW + i * Ws + j];
    float px = ox + (float)(n / 3 - 1) + (float)(i + 1);
    float py = oy + (float)(n % 3 - 1) + (float)(j + 1);
    float fx = floorf(px), fy = floorf(py);
    float x_lt = fminf(fmaxf(fx,       0.f), 95.f);
    float x_rb = fminf(fmaxf(fx + 1.f, 0.f), 95.f);
    float y_lt = fminf(fmaxf(fy,       0.f), 95.f);
    float y_rb = fminf(fmaxf(fy + 1.f, 0.f), 95.f);
    float pxc  = fminf(fmaxf(px, 0.f), 95.f);
    float pyc  = fminf(fmaxf(py, 0.f), 95.f);
    float g_lt = (1.f + (x_lt - pxc)) * (1.f + (y_lt - pyc));
    float g_rb = (1.f - (x_rb - pxc)) * (1.f - (y_rb - pyc));
    float g_lb = (1.f + (x_lt - pxc)) * (1.f - (y_rb - pyc));
    float g_rt = (1.f - (x_rb - pxc)) * (1.f + (y_lt - pyc));
    int ilt = (int)x_lt * Ws + (int)y_lt;
    int irb = (int)x_rb * Ws + (int)y_rb;
    int ilb = (int)x_lt * Ws + (int)y_rb;
    int irt = (int)x_rb * Ws + (int)y_lt;
    pidx[e] = make_int4(ilt, irb, ilb, irt);
    pw[e]   = make_float4(g_lt, g_rb, g_lb, g_rt);
}

// ---------------- MFMA GEMM, NHWC fill: 16 px x 128 oc per block, split-K x2 ----------------
// Input NHWC packed uint (hi|lo<<16). K-order: k = n*CIN + c; each 64-K step is one tap n.
// FILL LANES ARE CHANNEL-FASTEST: fc4 = tid&15, fpx = tid>>4 -> lanes 0..15 load 16
// consecutive uint4 of ONE pixel-neighbor = one 256B coalesced segment per 16-lane group.
// Software pipeline: bilinear(cur regs) -> issue next-step gather (same regs, WAR) ->
// barrier -> LDS write -> barrier -> MAC. Gather latency hides under write+barrier+MAC.
// 4 waves; wave w: oc slice [32w,32w+32). A = weights (m=oc), B = patch (n=px).
// D: col(lane&15)=px -> coalesced stores; row((lane>>4)*4+r)=oc.
template<int CIN, bool DEFORM, bool SPLIT3>
__global__ void mgemm_big_kernel(const uint* __restrict__ xT, const ushort* __restrict__ wp,
                                 const int4* __restrict__ pidx, const float4* __restrict__ pw,
                                 float* __restrict__ p0, float* __restrict__ p1) {
    constexpr int KS = CIN * 9 / 2;
    constexpr int NSTEP = KS / 64;
    constexpr int TILES = Bn * HW / 16;   // 1152
    __shared__ ushort Ah[16][80];         // [px][64k + pad] bf16 hi, col-swizzled
    __shared__ ushort Al[16][80];         // lo
    __shared__ int4  sidx[144];
    __shared__ float4 ssw[144];

    int tid = threadIdx.x;
    // XCD-aware swizzle: 2304 blocks, 8 XCDs, 288 contiguous per XCD
    int bid = blockIdx.x;
    int swz = (bid & 7) * 288 + (bid >> 3);
    int s = swz / TILES;
    int t = swz % TILES;
    int p0x = t * 16;
    int b = p0x / HW;
    int pin = p0x % HW;
    int irow = pin / Ws, j0 = pin % Ws;

    if constexpr (DEFORM) {
        if (tid < 144) {
            sidx[tid] = pidx[(size_t)p0x * N9 + tid];
            ssw[tid]  = pw[(size_t)p0x * N9 + tid];
        }
        __syncthreads();   // prologue gather below reads sidx
    }
    const uint* xbT = xT + (size_t)b * HW * CIN;
    const ushort* wlo = wp + (size_t)CIN * 9 * 128;
    int w = tid >> 6, lane = tid & 63;
    int lg = lane >> 4, l15 = lane & 15;
    int fpx = tid >> 4, fc4 = tid & 15;   // CHANNEL-FASTEST fill mapping

    f32x4 acc[2];
    acc[0] = (f32x4){0.f, 0.f, 0.f, 0.f};
    acc[1] = (f32x4){0.f, 0.f, 0.f, 0.f};
    int bswz = (l15 >> 2) << 3;           // read-side col swizzle (ushorts)
    int col = (fc4 * 4) ^ ((fpx >> 2) << 3);   // write-side swizzle (ushorts, 8B-aligned)

    uint4 qa, qb, qc, qd;
    // gather issue for step ks into qa..qd
    auto gload = [&](int ks) {
        int k0 = s * KS + ks * 64;
        int n = k0 / CIN;
        int cc = (k0 & (CIN - 1)) + fc4 * 4;
        if constexpr (DEFORM) {
            int4 i4 = sidx[fpx * 9 + n];
            qa = *(const uint4*)&xbT[(size_t)i4.x * CIN + cc];
            qb = *(const uint4*)&xbT[(size_t)i4.y * CIN + cc];
            qc = *(const uint4*)&xbT[(size_t)i4.z * CIN + cc];
            qd = *(const uint4*)&xbT[(size_t)i4.w * CIN + cc];
        } else {
            int n3 = n / 3;
            int rr = irow + n3 - 1, ccol = j0 + fpx + (n - 3 * n3) - 1;
            qa = make_uint4(0u, 0u, 0u, 0u);
            if (rr >= 0 && rr < Hs && ccol >= 0 && ccol < Ws)
                qa = *(const uint4*)&xbT[(size_t)(rr * Ws + ccol) * CIN + cc];
        }
    };
    gload(0);

    for (int ks = 0; ks < NSTEP; ks++) {
        int k0 = s * KS + ks * 64;
        // ---- consume regs -> h/l (bilinear for deform, bit-split for conv) ----
        ushort h[4], l[4];
        if constexpr (DEFORM) {
            int n = k0 / CIN;
            float4 w4 = ssw[fpx * 9 + n];
            uint ua[4] = {qa.x, qa.y, qa.z, qa.w};
            uint ub[4] = {qb.x, qb.y, qb.z, qb.w};
            uint uc[4] = {qc.x, qc.y, qc.z, qc.w};
            uint ud[4] = {qd.x, qd.y, qd.z, qd.w};
            #pragma unroll
            for (int j = 0; j < 4; j++) {
                float v = w4.x * (rchi(ua[j]) + rclo(ua[j]))
                        + w4.y * (rchi(ub[j]) + rclo(ub[j]))
                        + w4.z * (rchi(uc[j]) + rclo(uc[j]))
                        + w4.w * (rchi(ud[j]) + rclo(ud[j]));
                h[j] = bfbits(v);
                if constexpr (SPLIT3) l[j] = bfbits(v - bf2f(h[j]));
            }
        } else {
            uint ua[4] = {qa.x, qa.y, qa.z, qa.w};
            #pragma unroll
            for (int j = 0; j < 4; j++) {
                h[j] = (ushort)(ua[j] & 0xffffu);
                if constexpr (SPLIT3) l[j] = (ushort)(ua[j] >> 16);
            }
        }
        // ---- prefetch next step's gather (regs free after consume) ----
        if (ks + 1 < NSTEP) gload(ks + 1);
        __syncthreads();   // prior MAC done reading LDS
        uint2 wh; wh.x = packu(h[0], h[1]); wh.y = packu(h[2], h[3]);
        *(uint2*)&Ah[fpx][col] = wh;
        if constexpr (SPLIT3) {
            uint2 wl; wl.x = packu(l[0], l[1]); wl.y = packu(l[2], l[3]);
            *(uint2*)&Al[fpx][col] = wl;
        }
        __syncthreads();
        // ---- MAC: 2 K-halves; SPLIT3 -> ah*bh + ah*bl + al*bh ----
        #pragma unroll
        for (int kk = 0; kk < 2; kk++) {
            const ushort* wpk = wp + ((size_t)(k0 / 32 + kk) * 128) * 32;
            int bcol = (kk * 32 + lg * 8) ^ bswz;
            bf16x8 a0h = *(const bf16x8*)&wpk[(32 * w + l15) * 32 + lg * 8];
            bf16x8 a1h = *(const bf16x8*)&wpk[(32 * w + 16 + l15) * 32 + lg * 8];
            bf16x8 b0h = *(const bf16x8*)&Ah[l15][bcol];
            acc[0] = __builtin_amdgcn_mfma_f32_16x16x32_bf16(a0h, b0h, acc[0], 0, 0, 0);
            acc[1] = __builtin_amdgcn_mfma_f32_16x16x32_bf16(a1h, b0h, acc[1], 0, 0, 0);
            if constexpr (SPLIT3) {
                const ushort* wpl = wlo + ((size_t)(k0 / 32 + kk) * 128) * 32;
                bf16x8 a0l = *(const bf16x8*)&wpl[(32 * w + l15) * 32 + lg * 8];
                bf16x8 a1l = *(const bf16x8*)&wpl[(32 * w + 16 + l15) * 32 + lg * 8];
                bf16x8 b0l = *(const bf16x8*)&Al[l15][bcol];
                acc[0] = __builtin_amdgcn_mfma_f32_16x16x32_bf16(a0h, b0l, acc[0], 0, 0, 0);
                acc[0] = __builtin_amdgcn_mfma_f32_16x16x32_bf16(a0l, b0h, acc[0], 0, 0, 0);
                acc[1] = __builtin_amdgcn_mfma_f32_16x16x32_bf16(a1h, b0l, acc[1], 0, 0, 0);
                acc[1] = __builtin_amdgcn_mfma_f32_16x16x32_bf16(a1l, b0h, acc[1], 0, 0, 0);
            }
        }
    }
    float* pout = s ? p1 : p0;
    #pragma unroll
    for (int mf = 0; mf < 2; mf++) {
        int oc = 32 * w + 16 * mf + lg * 4;
        #pragma unroll
        for (int r = 0; r < 4; r++)
            pout[((size_t)b * OUTCH + oc + r) * HW + pin + l15] = acc[mf][r];
    }
}

// ---------------- combine split-K partials + bias + ReLU -> xcat[:, 0:128] ----------------
__global__ void combine_halve_kernel(const float* __restrict__ p0, const float* __restrict__ p1,
                                     const float* __restrict__ bias, float* __restrict__ xcat) {
    int idx = blockIdx.x * blockDim.x + threadIdx.x;
    const int total = Bn * OUTCH * HW;
    if (idx >= total) return;
    int b = idx / (OUTCH * HW);
    int o = (idx / HW) % OUTCH;
    int pin = idx % HW;
    float v = p0[idx] + p1[idx] + bias[o];
    xcat[((size_t)b * INCH + o) * HW + pin] = fmaxf(v, 0.f);
}

// ---------------- training-mode BN statistics over (p0+p1) ----------------
__global__ void bnstats_kernel(const float* __restrict__ p0, const float* __restrict__ p1,
                               float* __restrict__ mv) {
    int o = blockIdx.x;
    int tid = threadIdx.x;
    float s = 0.f, sq = 0.f;
    for (int k = tid; k < Bn * HW; k += 256) {
        int b = k / HW, p = k % HW;
        size_t idx = ((size_t)b * OUTCH + o) * HW + p;
        float v = p0[idx] + p1[idx];
        s += v; sq += v * v;
    }
    __shared__ float rs[256], rq[256];
    rs[tid] = s; rq[tid] = sq;
    __syncthreads();
    for (int st = 128; st > 0; st >>= 1) {
        if (tid < st) { rs[tid] += rs[tid + st]; rq[tid] += rq[tid + st]; }
        __syncthreads();
    }
    if (tid == 0) {
        float m = rs[0] / (float)(Bn * HW);
        mv[o] = m;
        mv[OUTCH + o] = rq[0] / (float)(Bn * HW) - m * m;
    }
}

// ---------------- BN apply + ReLU over (p0+p1) ----------------
__global__ void bnapply_kernel(const float* __restrict__ p0, const float* __restrict__ p1,
                               const float* __restrict__ mv,
                               const float* __restrict__ g, const float* __restrict__ be,
                               float* __restrict__ y) {
    int idx = blockIdx.x * blockDim.x + threadIdx.x;
    const int total = Bn * OUTCH * HW;
    if (idx >= total) return;
    int o = (idx / HW) % OUTCH;
    float m = mv[o], v = mv[OUTCH + o];
    float x = p0[idx] + p1[idx];
    float r = (x - m) / sqrtf(v + 1e-5f) * g[o] + be[o];
    y[idx] = fmaxf(r, 0.f);
}

extern "C" void kernel_launch(void* const* d_in, const int* in_sizes, int n_in,
                              void* d_out, int out_size, void* d_ws, size_t ws_size,
                              hipStream_t stream) {
    const float* x1   = (const float*)d_in[0];
    const float* x2   = (const float*)d_in[1];
    const float* chW  = (const float*)d_in[2];
    const float* chB  = (const float*)d_in[3];
    const float* p1W  = (const float*)d_in[4];
    const float* p1B  = (const float*)d_in[5];
    const float* c1W  = (const float*)d_in[6];
    const float* bn1g = (const float*)d_in[7];
    const float* bn1b = (const float*)d_in[8];
    const float* p2W  = (const float*)d_in[9];
    const float* p2B  = (const float*)d_in[10];
    const float* c2W  = (const float*)d_in[11];
    const float* bn2g = (const float*)d_in[12];
    const float* bn2b = (const float*)d_in[13];
    float* out = (float*)d_out;

    float* ws = (float*)d_ws;
    // Regions (floats): A=[0,4718592) B=[4718592,9437184) C=[9437184,11796480) D=[11796480,14155776)
    // Phase H: x2u@A -> x2uT@C∪D; cwThb@B[0..294912); mgemm: p0h@A[0), p1h@A[2359296);
    //          combine -> xcat@B; copy_x1 -> xcat@B
    // Stage 1: part@A, offb/pidx/pw/cwTb1@A tail; xcat@B -> xcatT@C∪D; p0d/p1d@B; y1@A[0)
    // Stage 2: part@B, offb/pidx/pw/cwTb2@B tail; y1@A -> y1T@C; p0d/p1d@A -> out
    float* x2u   = ws;
    uint*  x2uT  = (uint*)(ws + 9437184);
    ushort* cwThb = (ushort*)(ws + 4718592);
    float* p0h   = ws;
    float* p1h   = ws + 2359296;
    float* xcat  = ws + 4718592;

    float* part1 = ws;
    float* offb1 = ws + 2654208;
    int4*  pidx1 = (int4*)(ws + 2985984);
    float4* pw41 = (float4*)(ws + 3649536);
    ushort* cwTb1 = (ushort*)(ws + 4313088);
    uint*  xcatT = (uint*)(ws + 9437184);
    float* p0d1  = ws + 4718592;
    float* p1d1  = ws + 4718592 + 2359296;
    float* y1    = ws;

    float* part2 = ws + 4718592;
    float* offb2 = ws + 4718592 + 2654208;
    int4*  pidx2 = (int4*)(ws + 4718592 + 2985984);
    float4* pw42 = (float4*)(ws + 4718592 + 3649536);
    ushort* cwTb2 = (ushort*)(ws + 4718592 + 4313088);
    uint*  y1T   = (uint*)(ws + 9437184);
    float* p0d2  = ws;
    float* p1d2  = ws + 2359296;
    float* mv    = ws + 14155776;

    constexpr int BIG_GRID = 2 * Bn * HW / 16;          // 2304
    constexpr int T256_GRID = (HW/32) * (INCH/32) * Bn; // 4608
    constexpr int T128_GRID = (HW/32) * (OUTCH/32) * Bn;// 2304

    // ---- halve-channel conv ----
    up2_kernel<<<(Bn*INCH*HW + 255) / 256, 256, 0, stream>>>(x2, x2u);
    t_nhwc_kernel<INCH><<<T256_GRID, 256, 0, stream>>>(x2u, x2uT);
    wprep_big_kernel<INCH><<<(INCH*9*128 + 255) / 256, 256, 0, stream>>>(chW, cwThb);
    mgemm_big_kernel<INCH, false, true><<<BIG_GRID, 256, 0, stream>>>(x2uT, cwThb, nullptr, nullptr, p0h, p1h);
    combine_halve_kernel<<<(Bn*OUTCH*HW + 255) / 256, 256, 0, stream>>>(p0h, p1h, chB, xcat);
    copy_x1_kernel<<<(Bn*OUTCH*HW + 255) / 256, 256, 0, stream>>>(x1, xcat);

    // ---- stage 1 (offsets fp32; deform GEMM split-precision MFMA, NHWC coalesced fill) ----
    offconv_kernel<INCH, 8><<<8 * (Bn*HW/256), 256, 0, stream>>>(xcat, p1W, part1);
    offreduce_kernel<8><<<(Bn*18*HW + 255) / 256, 256, 0, stream>>>(part1, p1B, offb1);
    mkparams_kernel<<<(Bn*HW*N9 + 255) / 256, 256, 0, stream>>>(offb1, pidx1, pw41);
    wprep_big_kernel<INCH><<<(INCH*9*128 + 255) / 256, 256, 0, stream>>>(c1W, cwTb1);
    t_nhwc_kernel<INCH><<<T256_GRID, 256, 0, stream>>>(xcat, xcatT);
    mgemm_big_kernel<INCH, true, true><<<BIG_GRID, 256, 0, stream>>>(xcatT, cwTb1, pidx1, pw41, p0d1, p1d1);
    bnstats_kernel<<<OUTCH, 256, 0, stream>>>(p0d1, p1d1, mv);
    bnapply_kernel<<<(Bn*OUTCH*HW + 255) / 256, 256, 0, stream>>>(p0d1, p1d1, mv, bn1g, bn1b, y1);

    // ---- stage 2 (final output: plain bf16 MFMA) ----
    offconv_kernel<OUTCH, 8><<<8 * (Bn*HW/256), 256, 0, stream>>>(y1, p2W, part2);
    offreduce_kernel<8><<<(Bn*18*HW + 255) / 256, 256, 0, stream>>>(part2, p2B, offb2);
    mkparams_kernel<<<(Bn*HW*N9 + 255) / 256, 256, 0, stream>>>(offb2, pidx2, pw42);
    wprep_big_kernel<OUTCH><<<(OUTCH*9*128 + 255) / 256, 256, 0, stream>>>(c2W, cwTb2);
    t_nhwc_kernel<OUTCH><<<T128_GRID, 256, 0, stream>>>(y1, y1T);
    mgemm_big_kernel<OUTCH, true, false><<<BIG_GRID, 256, 0, stream>>>(y1T, cwTb2, pidx2, pw42, p0d2, p1d2);
    bnstats_kernel<<<OUTCH, 256, 0, stream>>>(p0d2, p1d2, mv);
    bnapply_kernel<<<(Bn*OUTCH*HW + 255) / 256, 256, 0, stream>>>(p0d2, p1d2, mv, bn2g, bn2b, out);
}